// Round 15
// baseline (258.690 us; speedup 1.0000x reference)
//
#include <hip/hip_runtime.h>

// GCN 2-layer on MI355X — Round 15: R14 + line-padded reservation cursors,
// EPB=4096 sortA, BC=8 localC with in-place flush + int2 run boundaries.
//
// g[j] = x[j]*dinv[j].  layer1: hs2 via relu(dinv*(sum g)+b1)@W2*dinv
// layer2: out[i] = dinv[i]*(sum hs2[src]+hs2[i]) + b2
//
// sortA: 4096 edges/block, 8 edges/thread in registers. Phase1 LDS hist over
//   dp=dst>>11; one global atomicAdd per (block,dp) on a PADDED cursor (one
//   64B line per dp -> no L2 hot-line serialization); phase2 places
//   packed=(ld<<18)|src from registers via block-shared LDS cursors.
// localC: block=(dp,b), b<8: in-place LDS counting sort of its eighth of the
//   dp region (hist 2048 -> scan -> stage -> coalesced flush back into the
//   SAME buffer) -> csr + runSE[(dp*8+b)] int2 {start,end} per localdst.
// agg: thread = node, 8 runs, register acc, fused dense epilogues.
//
// ws: cursor[128*16] | runSE[98*8*4096] | csr[98*CAP] | dinv|g|hs2  (~46 MB)

#define EPB   4096   // edges per sortA block
#define PART  2048   // nodes per partition
#define LPBIT 11
#define SRCB  18     // src bits in packed
#define BC    8      // localC sub-blocks per dp (= runs per node)
#define CAP   69632  // words per dp region (mean 65306 + ~17 sigma)
#define STCAP 8704   // localC stage words = ceil(CAP/8) -> never overflows
#define CURSTR 16    // cursor padding: one dp counter per 64B line

// ---------------- sortA: fused count + reserve + scatter ----------------

__global__ __launch_bounds__(512) void sortA_kernel(
    const int* __restrict__ src, const int* __restrict__ dst,
    int* __restrict__ cursor, unsigned* __restrict__ packed, int E, int P) {
    __shared__ int cnt[128];   // phase1 counts -> phase2 absolute cursors
    int tid = threadIdx.x;
    if (tid < 128) cnt[tid] = 0;
    __syncthreads();
    int nv4 = E >> 2;
    int b4 = blockIdx.x * (EPB >> 2);
    const int4* d4 = (const int4*)dst;
    const int4* s4 = (const int4*)src;
    // Phase 1: stash 2 int4 pairs in registers, histogram dp.
    int4 dv[2], sv[2];
    bool inb[2];
    #pragma unroll
    for (int k = 0; k < 2; k++) {
        int i = b4 + k * 512 + tid;
        inb[k] = (i < nv4);
        if (inb[k]) {
            dv[k] = d4[i];
            sv[k] = s4[i];
            atomicAdd(&cnt[dv[k].x >> LPBIT], 1);
            atomicAdd(&cnt[dv[k].y >> LPBIT], 1);
            atomicAdd(&cnt[dv[k].z >> LPBIT], 1);
            atomicAdd(&cnt[dv[k].w >> LPBIT], 1);
        }
    }
    bool lastblk = (blockIdx.x == gridDim.x - 1);
    int tsrc = 0, tdst = 0;
    bool tin = false;
    if (lastblk) {  // scalar tail (E % 4)
        int e = (nv4 << 2) + tid;
        tin = (e < E);
        if (tin) {
            tdst = dst[e];
            tsrc = src[e];
            atomicAdd(&cnt[tdst >> LPBIT], 1);
        }
    }
    __syncthreads();
    if (tid < 128) {
        int c = cnt[tid];
        int base = (c > 0) ? atomicAdd(&cursor[tid * CURSTR], c) : 0;
        cnt[tid] = tid * CAP + base;  // absolute cursor
    }
    __syncthreads();
    // Phase 2: place from registers.
    #pragma unroll
    for (int k = 0; k < 2; k++) {
        if (inb[k]) {
            int4 d = dv[k];
            int4 s = sv[k];
            int p0 = atomicAdd(&cnt[d.x >> LPBIT], 1);
            packed[p0] = ((unsigned)(d.x & (PART - 1)) << SRCB) | (unsigned)s.x;
            int p1 = atomicAdd(&cnt[d.y >> LPBIT], 1);
            packed[p1] = ((unsigned)(d.y & (PART - 1)) << SRCB) | (unsigned)s.y;
            int p2 = atomicAdd(&cnt[d.z >> LPBIT], 1);
            packed[p2] = ((unsigned)(d.z & (PART - 1)) << SRCB) | (unsigned)s.z;
            int p3 = atomicAdd(&cnt[d.w >> LPBIT], 1);
            packed[p3] = ((unsigned)(d.w & (PART - 1)) << SRCB) | (unsigned)s.w;
        }
    }
    if (tin) {
        int pos = atomicAdd(&cnt[tdst >> LPBIT], 1);
        packed[pos] = ((unsigned)(tdst & (PART - 1)) << SRCB) | (unsigned)tsrc;
    }
}

// ---------------- localC: in-place LDS counting sort per eighth ----------

__global__ __launch_bounds__(512) void localC_kernel(
    unsigned* __restrict__ csr,  // packed in, dst-sorted src out (in place)
    const int* __restrict__ cursor, int* __restrict__ runSE) {
    __shared__ int hist[PART];      // counts -> absolute cursors
    __shared__ int sdata[512];
    __shared__ unsigned stage[STCAP];
    int tid = threadIdx.x;
    int dp = blockIdx.x >> 3, b = blockIdx.x & (BC - 1);
    int dpbase = dp * CAP;
    int tot = cursor[dp * CURSTR];
    int lo = dpbase + (int)(((long long)tot * b) / BC);
    int hi = dpbase + (int)(((long long)tot * (b + 1)) / BC);
    for (int k = tid; k < PART; k += 512) hist[k] = 0;
    __syncthreads();
    for (int i = lo + tid; i < hi; i += 512)
        atomicAdd(&hist[csr[i] >> SRCB], 1);
    __syncthreads();
    // exclusive scan of hist[2048], 4 elems/thread
    int off = tid * 4;
    int v0 = hist[off], v1 = hist[off + 1], v2 = hist[off + 2], v3 = hist[off + 3];
    int s = v0 + v1 + v2 + v3;
    int x = s;
    sdata[tid] = x;
    __syncthreads();
    for (int o = 1; o < 512; o <<= 1) {
        int t = (tid >= o) ? sdata[tid - o] : 0;
        __syncthreads();
        x += t;
        sdata[tid] = x;
        __syncthreads();
    }
    int run = x - s;
    int c0 = lo + run, c1 = c0 + v0, c2 = c1 + v1, c3 = c2 + v2;
    int2* se = (int2*)(runSE + (size_t)(dp * BC + b) * (2 * PART));
    se[off]     = make_int2(c0, c1);
    se[off + 1] = make_int2(c1, c2);
    se[off + 2] = make_int2(c2, c3);
    se[off + 3] = make_int2(c3, c3 + v3);
    __syncthreads();
    hist[off] = c0; hist[off + 1] = c1; hist[off + 2] = c2; hist[off + 3] = c3;
    __syncthreads();
    // place into LDS stage (total = hi-lo <= ceil(CAP/8) = STCAP always)
    int total = hi - lo;
    for (int i = lo + tid; i < hi; i += 512) {
        unsigned w = csr[i];
        int pos = atomicAdd(&hist[w >> SRCB], 1);
        stage[pos - lo] = w & ((1u << SRCB) - 1);
    }
    __syncthreads();  // all csr reads done before in-place overwrite
    for (int j = tid; j < total; j += 512) csr[lo + j] = stage[j];
}

// ---------------- Node-side (atomic-free, thread-per-node) ----------------

__global__ __launch_bounds__(512) void dinvg_kernel(
    const int* __restrict__ runSE, const float* __restrict__ x,
    float* __restrict__ dinv, float* __restrict__ g, int n) {
    int i = blockIdx.x * 512 + threadIdx.x;
    if (i >= n) return;
    int dp = i >> LPBIT, ld = i & (PART - 1);
    int deg = 0;
    #pragma unroll
    for (int b = 0; b < BC; b++) {
        int2 se = ((const int2*)(runSE + (size_t)(dp * BC + b) * (2 * PART)))[ld];
        deg += se.y - se.x;
    }
    float d = rsqrtf((float)deg + 1.0f);  // +1 self-loop
    dinv[i] = d;
    float2 xv = ((const float2*)x)[i];
    ((float2*)g)[i] = make_float2(xv.x * d, xv.y * d);
}

// thread = node: 8 runs, gather g[src], register acc + fused W1/ReLU/W2.
__global__ __launch_bounds__(512) void agg1_kernel(
    const int* __restrict__ runSE, const unsigned* __restrict__ csr,
    const float* __restrict__ g, const float* __restrict__ dinv,
    const float* __restrict__ W1, const float* __restrict__ b1,
    const float* __restrict__ W2, float* __restrict__ hs2, int n) {
    int i = blockIdx.x * 512 + threadIdx.x;
    if (i >= n) return;
    int dp = i >> LPBIT, ld = i & (PART - 1);
    const float2* gp = (const float2*)g;
    float s0 = 0.0f, s1 = 0.0f;
    #pragma unroll
    for (int b = 0; b < BC; b++) {
        int2 se = ((const int2*)(runSE + (size_t)(dp * BC + b) * (2 * PART)))[ld];
        int p = se.x, p1 = se.y;
        for (; p + 4 <= p1; p += 4) {
            int a = csr[p], bb = csr[p + 1], c = csr[p + 2], e = csr[p + 3];
            float2 w0 = gp[a], w1 = gp[bb], w2 = gp[c], w3 = gp[e];
            s0 += w0.x + w1.x + w2.x + w3.x;
            s1 += w0.y + w1.y + w2.y + w3.y;
        }
        for (; p < p1; p++) {
            float2 w = gp[csr[p]];
            s0 += w.x;
            s1 += w.y;
        }
    }
    float d = dinv[i];
    float2 gi = gp[i];
    s0 = (s0 + gi.x) * d;
    s1 = (s1 + gi.y) * d;
    float h[8];
    #pragma unroll
    for (int f = 0; f < 8; f++)
        h[f] = fmaxf(s0 * W1[f] + s1 * W1[8 + f] + b1[f], 0.0f);
    float oc[4];
    #pragma unroll
    for (int k = 0; k < 4; k++) {
        float a = 0.0f;
        #pragma unroll
        for (int f = 0; f < 8; f++) a += h[f] * W2[4 * f + k];
        oc[k] = a * d;
    }
    float4 o;
    o.x = oc[0]; o.y = oc[1]; o.z = oc[2]; o.w = oc[3];
    *(float4*)(hs2 + 4 * (size_t)i) = o;
}

// thread = node: 8 runs, gather hs2[src], write final output.
__global__ __launch_bounds__(512) void agg2_kernel(
    const int* __restrict__ runSE, const unsigned* __restrict__ csr,
    const float* __restrict__ hs2, const float* __restrict__ dinv,
    const float* __restrict__ b2, float* __restrict__ out, int n) {
    int i = blockIdx.x * 512 + threadIdx.x;
    if (i >= n) return;
    int dp = i >> LPBIT, ld = i & (PART - 1);
    const float4* hp = (const float4*)hs2;
    float s0 = 0.0f, s1 = 0.0f, s2 = 0.0f, s3 = 0.0f;
    #pragma unroll
    for (int b = 0; b < BC; b++) {
        int2 se = ((const int2*)(runSE + (size_t)(dp * BC + b) * (2 * PART)))[ld];
        int p = se.x, p1 = se.y;
        for (; p + 4 <= p1; p += 4) {
            int a = csr[p], bb = csr[p + 1], c = csr[p + 2], e = csr[p + 3];
            float4 w0 = hp[a], w1 = hp[bb], w2 = hp[c], w3 = hp[e];
            s0 += w0.x + w1.x + w2.x + w3.x;
            s1 += w0.y + w1.y + w2.y + w3.y;
            s2 += w0.z + w1.z + w2.z + w3.z;
            s3 += w0.w + w1.w + w2.w + w3.w;
        }
        for (; p < p1; p++) {
            float4 w = hp[csr[p]];
            s0 += w.x; s1 += w.y; s2 += w.z; s3 += w.w;
        }
    }
    float d = dinv[i];
    float4 hi2 = hp[i];
    float4 o;
    o.x = d * (s0 + hi2.x) + b2[0];
    o.y = d * (s1 + hi2.y) + b2[1];
    o.z = d * (s2 + hi2.z) + b2[2];
    o.w = d * (s3 + hi2.w) + b2[3];
    *(float4*)(out + 4 * (size_t)i) = o;
}

extern "C" void kernel_launch(void* const* d_in, const int* in_sizes, int n_in,
                              void* d_out, int out_size, void* d_ws, size_t ws_size,
                              hipStream_t stream) {
    const float* x   = (const float*)d_in[0];
    const int*   ei  = (const int*)d_in[1];
    const float* W1  = (const float*)d_in[2];
    const float* b1  = (const float*)d_in[3];
    const float* W2  = (const float*)d_in[4];
    const float* b2  = (const float*)d_in[5];
    float* out = (float*)d_out;

    const int n = in_sizes[0] / 2;  // x is [N,2]
    const int E = in_sizes[1] / 2;  // edge_index is [2,E]
    const int* src = ei;
    const int* dst = ei + E;

    const int P  = (n + PART - 1) >> LPBIT;  // 98
    const int B1 = (E + EPB - 1) / EPB;      // 1563

    int* ws = (int*)d_ws;
    int* cursor = ws;                                        // 128*16 = 2048
    int* runSE = ws + 128 * CURSTR;                          // P*BC*2*PART
    size_t sesz = (size_t)P * BC * 2 * PART;                 // 3,211,264
    unsigned* csr = (unsigned*)(runSE + sesz);               // P*CAP (in-place)
    size_t nd = (size_t)P << LPBIT;                          // 200704
    float* dinv = (float*)(csr + (size_t)P * CAP);           // nd
    float* g    = dinv + nd;                                 // 2*nd
    float* hs2  = g + 2 * nd;                                // 4*nd

    hipMemsetAsync(cursor, 0, 128 * CURSTR * sizeof(int), stream);

    const int gN = (n + 511) / 512;  // 391

    sortA_kernel <<<B1, 512, 0, stream>>>(src, dst, cursor, csr, E, P);
    localC_kernel<<<P * BC, 512, 0, stream>>>(csr, cursor, runSE);
    dinvg_kernel <<<gN, 512, 0, stream>>>(runSE, x, dinv, g, n);
    agg1_kernel  <<<gN, 512, 0, stream>>>(runSE, csr, g, dinv, W1, b1, W2, hs2, n);
    agg2_kernel  <<<gN, 512, 0, stream>>>(runSE, csr, hs2, dinv, b2, out, n);
}